// Round 2
// baseline (1536.606 us; speedup 1.0000x reference)
//
#include <hip/hip_runtime.h>
#include <hip/hip_bf16.h>
#include <math.h>

#define BB 16
#define LL 4095
#define DD 768
#define TT 768
#define SS 64
#define KK 8
#define HH 384
#define G3 1152   // 3*H

// ---------- 1. span means ----------
__global__ void span_mean_kernel(const float* __restrict__ hidden,
                                 const int* __restrict__ sstart,
                                 const int* __restrict__ slen,
                                 float* __restrict__ span) {
    int bs = blockIdx.x;            // b*64+s
    int b = bs >> 6;
    int st = sstart[bs];
    int ln = slen[bs];
    const float* base = hidden + ((size_t)b * LL + st) * DD;
    float inv = 1.0f / (float)ln;
    for (int d = threadIdx.x; d < DD; d += 256) {
        float acc = 0.0f;
        for (int r = 0; r < ln; ++r) acc += base[(size_t)r * DD + d];
        span[(size_t)bs * DD + d] = acc * inv;
    }
}

// ---------- 2. ctx accumulation (atomic partial sums) ----------
__global__ void ctx_accum_kernel(const float* __restrict__ hidden,
                                 const int* __restrict__ attn_len,
                                 float* __restrict__ ctx) {
    int b = blockIdx.x, chunk = blockIdx.y;
    int lim = attn_len[b] - 1;
    int l0 = chunk * 128;
    int l1 = min(l0 + 128, lim);
    if (l0 >= l1) return;
    int t = threadIdx.x;
    const float* base = hidden + (size_t)b * LL * DD;
    float a0 = 0.f, a1 = 0.f, a2 = 0.f;
    for (int l = l0; l < l1; ++l) {
        const float* row = base + (size_t)l * DD;
        a0 += row[t]; a1 += row[t + 256]; a2 += row[t + 512];
    }
    atomicAdd(&ctx[b * DD + t], a0);
    atomicAdd(&ctx[b * DD + t + 256], a1);
    atomicAdd(&ctx[b * DD + t + 512], a2);
}

// ---------- 3. rep_context = (ctx/n) @ W_ctx^T + b_ctx ----------
__global__ void repctx_kernel(const float* __restrict__ ctxsum,
                              const int* __restrict__ attn_len,
                              const float* __restrict__ W_ctx,
                              const float* __restrict__ b_ctx,
                              float* __restrict__ out_rc) {
    int b = blockIdx.x;
    int j = blockIdx.y * 256 + threadIdx.x;
    __shared__ float cv[DD];
    float inv = 1.0f / (float)(attn_len[b] - 1);
    for (int d = threadIdx.x; d < DD; d += 256) cv[d] = ctxsum[b * DD + d] * inv;
    __syncthreads();
    const float* wr = W_ctx + (size_t)j * DD;
    float acc = b_ctx[j];
    for (int d = 0; d < DD; ++d) acc += wr[d] * cv[d];
    out_rc[b * TT + j] = acc;
}

// ---------- 4. transpose W_hh (fp32), layout [dir][k4][gate][i] as float4 ----------
__global__ void whh_pack_kernel(const float* __restrict__ Wf,
                                const float* __restrict__ Wb,
                                float* __restrict__ wtb) {
    int o = blockIdx.x * 256 + threadIdx.x;   // [0, 2*96*3*384)
    if (o >= 2 * 96 * 3 * 384) return;
    int i = o % 384;
    int r = o / 384;
    int g = r % 3; r /= 3;
    int k4 = r % 96;
    int dir = r / 96;
    const float* W = dir ? Wb : Wf;
    int j = g * HH + i;
    const float* wrow = W + (size_t)j * HH + k4 * 4;
    float4 v;
    v.x = wrow[0]; v.y = wrow[1]; v.z = wrow[2]; v.w = wrow[3];
    ((float4*)wtb)[o] = v;
}

// ---------- 5. gi = span @ W_ih^T + b_ih (+ b_hh for r,z gates) ----------
__global__ __launch_bounds__(256) void gi_gemm_kernel(
        const float* __restrict__ span,
        const float* __restrict__ Wf, const float* __restrict__ Wb,
        const float* __restrict__ bihf, const float* __restrict__ bhhf,
        const float* __restrict__ bihb, const float* __restrict__ bhhb,
        float* __restrict__ gi) {
    int dir = blockIdx.z;
    const float* W = dir ? Wb : Wf;
    const float* bih = dir ? bihb : bihf;
    const float* bhh = dir ? bhhb : bhhf;
    int m0 = blockIdx.x * 64, n0 = blockIdx.y * 64;
    __shared__ float As[64][17];
    __shared__ float Bs[64][17];
    int t = threadIdx.x, tx = t & 15, ty = t >> 4;
    float acc[4][4] = {{0.f}};
    for (int k0 = 0; k0 < DD; k0 += 16) {
        for (int e = t; e < 1024; e += 256) {
            int r = e >> 4, c = e & 15;
            As[r][c] = span[(size_t)(m0 + r) * DD + k0 + c];
            Bs[r][c] = W[(size_t)(n0 + r) * DD + k0 + c];
        }
        __syncthreads();
#pragma unroll
        for (int kk = 0; kk < 16; ++kk) {
            float a[4], bv[4];
#pragma unroll
            for (int i = 0; i < 4; ++i) a[i] = As[ty * 4 + i][kk];
#pragma unroll
            for (int j = 0; j < 4; ++j) bv[j] = Bs[tx * 4 + j][kk];
#pragma unroll
            for (int i = 0; i < 4; ++i)
#pragma unroll
                for (int j = 0; j < 4; ++j) acc[i][j] += a[i] * bv[j];
        }
        __syncthreads();
    }
#pragma unroll
    for (int i = 0; i < 4; ++i)
#pragma unroll
        for (int j = 0; j < 4; ++j) {
            int m = m0 + ty * 4 + i, n = n0 + tx * 4 + j;
            float v = acc[i][j] + bih[n] + (n < 2 * HH ? bhh[n] : 0.0f);
            gi[((size_t)dir * 1024 + m) * G3 + n] = v;
        }
}

// ---------- 6. GRU scan: one WG per (b,dir), W_hh streamed fp32 from L2 ----------
__global__ __launch_bounds__(384) void scan_kernel(
        const float* __restrict__ gi,
        const float* __restrict__ wtb,
        const float* __restrict__ bhhf, const float* __restrict__ bhhb,
        float* __restrict__ repac) {
    int b = blockIdx.x & 15, dir = blockIdx.x >> 4;
    int i = threadIdx.x;  // 0..383
    __shared__ float hA[HH];
    __shared__ float hB[HH];
    const float* gib = gi + ((size_t)dir * 1024 + b * 64) * G3;
    const float4* wp = ((const float4*)wtb) + (size_t)dir * 96 * 3 * 384;
    float bhn = (dir ? bhhb : bhhf)[2 * HH + i];
    hA[i] = 0.0f;
    __syncthreads();
    float* hc = hA;
    float* hn = hB;
    for (int step = 0; step < 64; ++step) {
        int s = dir ? (63 - step) : step;
        const float* grow = gib + (size_t)s * G3;
        float gr = grow[i], gz = grow[HH + i], gn = grow[2 * HH + i];
        float ar = 0.f, az = 0.f, an = 0.f;
        const float4* h4 = (const float4*)hc;
#pragma unroll 4
        for (int k4 = 0; k4 < 96; ++k4) {
            float4 hv = h4[k4];
            float4 w0 = wp[(k4 * 3 + 0) * 384 + i];
            float4 w1 = wp[(k4 * 3 + 1) * 384 + i];
            float4 w2 = wp[(k4 * 3 + 2) * 384 + i];
            ar += w0.x * hv.x + w0.y * hv.y + w0.z * hv.z + w0.w * hv.w;
            az += w1.x * hv.x + w1.y * hv.y + w1.z * hv.z + w1.w * hv.w;
            an += w2.x * hv.x + w2.y * hv.y + w2.z * hv.z + w2.w * hv.w;
        }
        float r = 1.0f / (1.0f + expf(-(gr + ar)));
        float z = 1.0f / (1.0f + expf(-(gz + az)));
        float n = tanhf(gn + r * (an + bhn));
        float hnew = (1.0f - z) * n + z * hc[i];
        hn[i] = hnew;
        repac[((size_t)(b * 64 + s)) * TT + dir * HH + i] = hnew;
        __syncthreads();
        float* tmp = hc; hc = hn; hn = tmp;
    }
}

// ---------- 7. q and k dot products (one wave each, fp64 accumulation) ----------
__global__ void qkv_kernel(const float* __restrict__ repac,
                           const float* __restrict__ repctx,
                           const float* __restrict__ Wfind,
                           float* __restrict__ qv, float* __restrict__ kv) {
    int w = blockIdx.x * 4 + (threadIdx.x >> 6);
    int lane = threadIdx.x & 63;
    const float* row;
    const float* vec;
    float* dst;
    if (w < 1024) {
        row = repac + (size_t)w * TT;
        vec = Wfind;
        dst = qv + w;
    } else {
        int u = w - 1024;
        int b = u / 65, j = u % 65;
        row = (j < 64) ? (repac + (size_t)(b * 64 + j) * TT) : (repctx + (size_t)b * TT);
        vec = Wfind + TT;
        dst = kv + u;
    }
    double acc = 0.0;
    for (int d = lane; d < TT; d += 64) acc += (double)row[d] * (double)vec[d];
#pragma unroll
    for (int off = 32; off > 0; off >>= 1) acc += __shfl_down(acc, off);
    if (lane == 0) *dst = (float)acc;
}

// ---------- 8. top-k on fp32-quantized scores (np-mirrored), tie -> lower idx ----------
__global__ void topk_kernel(const float* __restrict__ qv,
                            const float* __restrict__ kv,
                            float* __restrict__ vals_out,
                            float* __restrict__ idx_out,
                            int* __restrict__ idxw) {
    int t = threadIdx.x;
    int bs = blockIdx.x * 256 + t;
    int b = bs >> 6;
    int b0 = (blockIdx.x * 256) >> 6;       // 4 batches per block
    __shared__ float kvs[4 * 65];
    for (int e = t; e < 4 * 65; e += 256) kvs[e] = kv[(b0 + e / 65) * 65 + e % 65];
    __syncthreads();
    const float* myk = kvs + (b - b0) * 65;
    float q = qv[bs];
    // precompute fp32 scores exactly as np: s = 1f/(1f + float(exp(-double(x))))
    float sc[65];
#pragma unroll 1
    for (int j = 0; j < 65; ++j) {
        float x = q + myk[j];                 // fp32 add, as np broadcast-add
        float e = (float)exp(-(double)x);     // ~correctly-rounded f32 exp
        sc[j] = 1.0f / (1.0f + e);            // fp32 add + fp32 divide, as np
    }
    unsigned long long taken = 0ull;
    bool tk64 = false;
    for (int kk = 0; kk < 8; ++kk) {
        float best = -3.0e38f;
        int bj = 0;
        for (int j = 0; j < 65; ++j) {
            bool tkn = (j < 64) ? (((taken >> j) & 1ull) != 0ull) : tk64;
            float v = sc[j];
            if (!tkn && v > best) { best = v; bj = j; }   // strict > => lowest index wins ties
        }
        if (bj < 64) taken |= (1ull << bj); else tk64 = true;
        vals_out[bs * 8 + kk] = best;
        idx_out[bs * 8 + kk] = (float)bj;
        idxw[bs * 8 + kk] = bj;
    }
}

// ---------- 9. v1 gather ----------
__global__ void v1_kernel(const float* __restrict__ repac,
                          const float* __restrict__ repctx,
                          const int* __restrict__ idxw,
                          float* __restrict__ v1) {
    int bs = blockIdx.x;
    int b = bs >> 6;
    int t = threadIdx.x;
    for (int kk = 0; kk < 8; ++kk) {
        int j = idxw[bs * 8 + kk];
        const float* src = (j < 64) ? (repac + (size_t)(b * 64 + j) * TT)
                                    : (repctx + (size_t)b * TT);
        float* dst = v1 + ((size_t)bs * 8 + kk) * TT;
        for (int d = t; d < TT; d += 256) dst[d] = src[d];
    }
}

extern "C" void kernel_launch(void* const* d_in, const int* in_sizes, int n_in,
                              void* d_out, int out_size, void* d_ws, size_t ws_size,
                              hipStream_t stream) {
    const float* hidden    = (const float*)d_in[0];
    const float* W_ih_f    = (const float*)d_in[1];
    const float* W_hh_f    = (const float*)d_in[2];
    const float* b_ih_f    = (const float*)d_in[3];
    const float* b_hh_f    = (const float*)d_in[4];
    const float* W_ih_b    = (const float*)d_in[5];
    const float* W_hh_b    = (const float*)d_in[6];
    const float* b_ih_b    = (const float*)d_in[7];
    const float* b_hh_b    = (const float*)d_in[8];
    const float* W_ctx     = (const float*)d_in[9];
    const float* b_ctx     = (const float*)d_in[10];
    const float* W_find    = (const float*)d_in[11];
    const int*   attn_len  = (const int*)d_in[12];
    const int*   span_start= (const int*)d_in[13];
    const int*   span_len  = (const int*)d_in[14];
    (void)in_sizes; (void)n_in; (void)out_size; (void)ws_size;

    // workspace layout (floats)
    float* ws   = (float*)d_ws;
    float* span = ws;                       // 1024*768          = 786432
    float* gi   = span + 786432;            // 2*1024*1152       = 2359296
    float* ctx  = gi + 2359296;             // 16*768            = 12288
    float* qv   = ctx + 12288;              // 1024
    float* kv   = qv + 1024;                // 16*65 = 1040
    int*   idxw = (int*)(kv + 1040);        // 8192
    float* wtb  = (float*)(idxw + 8192);    // 2*96*3*384*4 fp32 = 884736*4 elems

    // output layout (floats)
    float* out      = (float*)d_out;
    float* o_repac  = out;                  // 786432
    float* o_repctx = out + 786432;         // 12288
    float* o_v1     = out + 798720;         // 6291456
    float* o_vals   = out + 7090176;        // 8192
    float* o_idx    = out + 7098368;        // 8192

    hipMemsetAsync(ctx, 0, (size_t)BB * DD * sizeof(float), stream);

    span_mean_kernel<<<1024, 256, 0, stream>>>(hidden, span_start, span_len, span);
    ctx_accum_kernel<<<dim3(BB, 32), 256, 0, stream>>>(hidden, attn_len, ctx);
    repctx_kernel<<<dim3(BB, 3), 256, 0, stream>>>(ctx, attn_len, W_ctx, b_ctx, o_repctx);
    whh_pack_kernel<<<864, 256, 0, stream>>>(W_hh_f, W_hh_b, wtb);
    gi_gemm_kernel<<<dim3(16, 18, 2), 256, 0, stream>>>(span, W_ih_f, W_ih_b,
                                                        b_ih_f, b_hh_f, b_ih_b, b_hh_b, gi);
    scan_kernel<<<32, 384, 0, stream>>>(gi, wtb, b_hh_f, b_hh_b, o_repac);
    qkv_kernel<<<516, 256, 0, stream>>>(o_repac, o_repctx, W_find, qv, kv);
    topk_kernel<<<4, 256, 0, stream>>>(qv, kv, o_vals, o_idx, idxw);
    v1_kernel<<<1024, 256, 0, stream>>>(o_repac, o_repctx, idxw, o_v1);
}